// Round 5
// baseline (714.021 us; speedup 1.0000x reference)
//
#include <hip/hip_runtime.h>
#include <hip/hip_cooperative_groups.h>

namespace cg = cooperative_groups;

// Otsu binarization: rgb(16,1024,1024,3) -> gray -> global otsu threshold -> {0,1}
// R3 lesson: kernels sum to ~110us but dur_us=388 -> launch/gap overhead
// dominates. ONE cooperative kernel with grid.sync() phases.
// R4 lesson: __shared__ union with ctor doesn't compile -> raw char LDS arena.
// d_out doubles as the gray buffer; ws holds minmax/hist partials + thresh.
//
// FP discipline (unchanged from the absmax=0 R3 version): __f*_rn everywhere,
// einsum L-to-R order, true division for bin index, sequential cumsums on one
// thread. One flipped pixel fails absmax, so no FMA/rcp tricks.

static constexpr float W0 = 0.2989f;
static constexpr float W1 = 0.5870f;
static constexpr float W2 = 0.1140f;

__device__ __forceinline__ float gray_of(float r, float g, float b) {
    // einsum 'bhwc,c->bhw': ((r*w0) + (g*w1)) + (b*w2), rn each step, no fma
    return __fadd_rn(__fadd_rn(__fmul_rn(r, W0), __fmul_rn(g, W1)), __fmul_rn(b, W2));
}

__device__ __forceinline__ void wave_minmax(float& lmin, float& lmax) {
    #pragma unroll
    for (int off = 32; off > 0; off >>= 1) {
        lmin = fminf(lmin, __shfl_down(lmin, off));
        lmax = fmaxf(lmax, __shfl_down(lmax, off));
    }
}

// ---------------- fused cooperative kernel ----------------
__global__ __launch_bounds__(256, 4) void k_fused(
        const float4* __restrict__ in4, float4* __restrict__ gray4,
        float* __restrict__ pmin, float* __restrict__ pmax,
        unsigned* __restrict__ hist_part, float* __restrict__ thresh,
        int ntiles, int npix4) {
    cg::grid_group grid = cg::this_grid();
    // Phase-overlapped LDS arena (phases are barrier-separated):
    //  A: float4 stage[768]                       = 12288 B
    //  C: unsigned lh[1024]                       =  4096 B
    //  D: float counts/centers/tt/w1/s1/w2/s2/vv  =  9216 B
    __shared__ __align__(16) char smraw[12288];
    float4*   stage   = (float4*)smraw;
    unsigned* lh      = (unsigned*)smraw;
    float*    counts  = (float*)smraw;
    float*    centers = counts + 256;
    float*    tt      = counts + 512;
    float*    w1      = counts + 768;
    float*    s1      = counts + 1024;
    float*    w2      = counts + 1280;
    float*    s2      = counts + 1536;
    float*    vv      = counts + 1792;
    __shared__ float sredA[4], sredB[4];
    __shared__ float s_mn, s_mx;

    const int t = threadIdx.x;
    const int bid = blockIdx.x;
    const int nb = gridDim.x;

    // ---- Phase A: gray + per-block min/max (LDS-staged coalesced loads) ----
    float lmin = __uint_as_float(0x7f800000u);   // +inf
    float lmax = -lmin;
    for (int tile = bid; tile < ntiles; tile += nb) {
        const float4* src = in4 + (size_t)tile * 768;
        float4 v0 = src[t];            // issue before barrier: latency overlaps
        float4 v1 = src[t + 256];
        float4 v2 = src[t + 512];
        __syncthreads();               // prior iteration's LDS reads done
        stage[t] = v0; stage[t + 256] = v1; stage[t + 512] = v2;
        __syncthreads();
        float4 a = stage[3 * t + 0];
        float4 b = stage[3 * t + 1];
        float4 c = stage[3 * t + 2];
        float g0 = gray_of(a.x, a.y, a.z);
        float g1 = gray_of(a.w, b.x, b.y);
        float g2 = gray_of(b.z, b.w, c.x);
        float g3 = gray_of(c.y, c.z, c.w);
        float4 o; o.x = g0; o.y = g1; o.z = g2; o.w = g3;
        gray4[(size_t)tile * 256 + t] = o;
        lmin = fminf(lmin, fminf(fminf(g0, g1), fminf(g2, g3)));
        lmax = fmaxf(lmax, fmaxf(fmaxf(g0, g1), fmaxf(g2, g3)));
    }
    wave_minmax(lmin, lmax);
    if ((t & 63) == 0) { sredA[t >> 6] = lmin; sredB[t >> 6] = lmax; }
    __syncthreads();
    if (t == 0) {
        pmin[bid] = fminf(fminf(sredA[0], sredA[1]), fminf(sredA[2], sredA[3]));
        pmax[bid] = fmaxf(fmaxf(sredB[0], sredB[1]), fmaxf(sredB[2], sredB[3]));
    }
    grid.sync();

    // ---- Phase B: every block redundantly reduces partials (L2-resident) ----
    lmin = __uint_as_float(0x7f800000u);
    lmax = -lmin;
    for (int i = t; i < nb; i += 256) {
        lmin = fminf(lmin, pmin[i]);
        lmax = fmaxf(lmax, pmax[i]);
    }
    wave_minmax(lmin, lmax);
    __syncthreads();                   // sredA/B reuse
    if ((t & 63) == 0) { sredA[t >> 6] = lmin; sredB[t >> 6] = lmax; }
    __syncthreads();
    if (t == 0) {
        s_mn = fminf(fminf(sredA[0], sredA[1]), fminf(sredA[2], sredA[3]));
        s_mx = fmaxf(fmaxf(sredB[0], sredB[1]), fmaxf(sredB[2], sredB[3]));
    }
    __syncthreads();
    const float mn = s_mn;
    const float mx = s_mx;
    const float width = __fdiv_rn(__fsub_rn(mx, mn), 256.0f);

    // ---- Phase C: per-wave LDS histograms -> per-block partial ----
    for (int j = t; j < 1024; j += 256) lh[j] = 0u;
    __syncthreads();
    unsigned* myh = &lh[(t >> 6) << 8];
    for (int i = bid * 256 + t; i < npix4; i += nb * 256) {
        float4 g = gray4[i];
        // reference: int32((x - mn) / width) clipped to [0,255] — true division
        int i0 = (int)__fdiv_rn(__fsub_rn(g.x, mn), width);
        int i1 = (int)__fdiv_rn(__fsub_rn(g.y, mn), width);
        int i2 = (int)__fdiv_rn(__fsub_rn(g.z, mn), width);
        int i3 = (int)__fdiv_rn(__fsub_rn(g.w, mn), width);
        i0 = min(max(i0, 0), 255);
        i1 = min(max(i1, 0), 255);
        i2 = min(max(i2, 0), 255);
        i3 = min(max(i3, 0), 255);
        atomicAdd(&myh[i0], 1u);   // LDS atomics only
        atomicAdd(&myh[i1], 1u);
        atomicAdd(&myh[i2], 1u);
        atomicAdd(&myh[i3], 1u);
    }
    __syncthreads();
    unsigned hsum = lh[t] + lh[256 + t] + lh[512 + t] + lh[768 + t];
    hist_part[(size_t)bid * 256 + t] = hsum;
    grid.sync();

    // ---- Phase D: block 0 sums partials + bit-exact sequential Otsu ----
    if (bid == 0) {
        unsigned c = 0;
        #pragma unroll 8
        for (int k = 0; k < nb; ++k)          // coalesced over t for each k
            c += hist_part[(size_t)k * 256 + t];
        __syncthreads();                      // lh alias dead before counts write
        counts[t] = (float)c;                 // exact: counts <= 2^24
        centers[t] = __fadd_rn(mn, __fmul_rn(width, __fadd_rn((float)t, 0.5f)));
        tt[t] = __fmul_rn(counts[t], centers[t]);
        __syncthreads();
        if (t == 0) {
            float aw = 0.0f, as = 0.0f;
            #pragma unroll 16
            for (int i = 0; i < 256; ++i) {   // forward cumsum (np order)
                aw = __fadd_rn(aw, counts[i]); w1[i] = aw;
                as = __fadd_rn(as, tt[i]);     s1[i] = as;
            }
            aw = 0.0f; as = 0.0f;
            #pragma unroll 16
            for (int i = 255; i >= 0; --i) {  // reversed cumsum
                aw = __fadd_rn(aw, counts[i]); w2[i] = aw;
                as = __fadd_rn(as, tt[i]);     s2[i] = as;
            }
        }
        __syncthreads();
        if (t < 255) {
            float m1 = __fdiv_rn(s1[t],     fmaxf(w1[t],     1.0f));
            float m2 = __fdiv_rn(s2[t + 1], fmaxf(w2[t + 1], 1.0f));
            float d  = __fsub_rn(m1, m2);
            // python eval order: (w1*w2) * (d**2)
            vv[t] = __fmul_rn(__fmul_rn(w1[t], w2[t + 1]), __fmul_rn(d, d));
        }
        __syncthreads();
        if (t == 0) {
            float best = -1.0f; int bi = 0;
            #pragma unroll 16
            for (int i = 0; i < 255; ++i) {   // strict > == first argmax
                float v = vv[i];
                if (v > best) { best = v; bi = i; }
            }
            thresh[0] = centers[bi];
        }
    }
    grid.sync();

    // ---- Phase E: binarize gray in place ----
    const float th = thresh[0];
    for (int i = bid * 256 + t; i < npix4; i += nb * 256) {
        float4 g = gray4[i];
        float4 o;
        o.x = g.x > th ? 1.0f : 0.0f;
        o.y = g.y > th ? 1.0f : 0.0f;
        o.z = g.z > th ? 1.0f : 0.0f;
        o.w = g.w > th ? 1.0f : 0.0f;
        gray4[i] = o;
    }
}

// ---------------- fallback path (R3 structure, known-good) ----------------
__global__ __launch_bounds__(256) void k_gray(
        const float4* __restrict__ in4, float4* __restrict__ gray4,
        float* __restrict__ pmin, float* __restrict__ pmax, int ntiles) {
    __shared__ float4 sv[768];
    int t = threadIdx.x;
    float lmin = __uint_as_float(0x7f800000u);
    float lmax = -lmin;
    for (int tile = blockIdx.x; tile < ntiles; tile += gridDim.x) {
        const float4* src = in4 + (size_t)tile * 768;
        float4 v0 = src[t];
        float4 v1 = src[t + 256];
        float4 v2 = src[t + 512];
        __syncthreads();
        sv[t] = v0; sv[t + 256] = v1; sv[t + 512] = v2;
        __syncthreads();
        float4 a = sv[3 * t + 0];
        float4 b = sv[3 * t + 1];
        float4 c = sv[3 * t + 2];
        float g0 = gray_of(a.x, a.y, a.z);
        float g1 = gray_of(a.w, b.x, b.y);
        float g2 = gray_of(b.z, b.w, c.x);
        float g3 = gray_of(c.y, c.z, c.w);
        float4 o; o.x = g0; o.y = g1; o.z = g2; o.w = g3;
        gray4[(size_t)tile * 256 + t] = o;
        lmin = fminf(lmin, fminf(fminf(g0, g1), fminf(g2, g3)));
        lmax = fmaxf(lmax, fmaxf(fmaxf(g0, g1), fmaxf(g2, g3)));
    }
    wave_minmax(lmin, lmax);
    __shared__ float smin[4], smax[4];
    if ((t & 63) == 0) { smin[t >> 6] = lmin; smax[t >> 6] = lmax; }
    __syncthreads();
    if (t == 0) {
        pmin[blockIdx.x] = fminf(fminf(smin[0], smin[1]), fminf(smin[2], smin[3]));
        pmax[blockIdx.x] = fmaxf(fmaxf(smax[0], smax[1]), fmaxf(smax[2], smax[3]));
    }
}

__global__ __launch_bounds__(256) void k_reduce(
        const float* __restrict__ pmin, const float* __restrict__ pmax,
        float* __restrict__ minmax, int n) {
    int t = threadIdx.x;
    float lmin = __uint_as_float(0x7f800000u);
    float lmax = -lmin;
    for (int i = t; i < n; i += 256) {
        lmin = fminf(lmin, pmin[i]);
        lmax = fmaxf(lmax, pmax[i]);
    }
    wave_minmax(lmin, lmax);
    __shared__ float smin[4], smax[4];
    if ((t & 63) == 0) { smin[t >> 6] = lmin; smax[t >> 6] = lmax; }
    __syncthreads();
    if (t == 0) {
        minmax[0] = fminf(fminf(smin[0], smin[1]), fminf(smin[2], smin[3]));
        minmax[1] = fmaxf(fmaxf(smax[0], smax[1]), fmaxf(smax[2], smax[3]));
    }
}

__global__ __launch_bounds__(256) void k_hist(
        const float4* __restrict__ gray4, const float* __restrict__ minmax,
        unsigned* __restrict__ hist_part, int npix4) {
    __shared__ unsigned lh[1024];
    for (int j = threadIdx.x; j < 1024; j += 256) lh[j] = 0u;
    __syncthreads();
    float mn = minmax[0];
    float mx = minmax[1];
    float width = __fdiv_rn(__fsub_rn(mx, mn), 256.0f);
    unsigned* myh = &lh[(threadIdx.x >> 6) << 8];
    int stride = gridDim.x * blockDim.x;
    for (int i = blockIdx.x * blockDim.x + threadIdx.x; i < npix4; i += stride) {
        float4 g = gray4[i];
        int i0 = (int)__fdiv_rn(__fsub_rn(g.x, mn), width);
        int i1 = (int)__fdiv_rn(__fsub_rn(g.y, mn), width);
        int i2 = (int)__fdiv_rn(__fsub_rn(g.z, mn), width);
        int i3 = (int)__fdiv_rn(__fsub_rn(g.w, mn), width);
        i0 = min(max(i0, 0), 255);
        i1 = min(max(i1, 0), 255);
        i2 = min(max(i2, 0), 255);
        i3 = min(max(i3, 0), 255);
        atomicAdd(&myh[i0], 1u);
        atomicAdd(&myh[i1], 1u);
        atomicAdd(&myh[i2], 1u);
        atomicAdd(&myh[i3], 1u);
    }
    __syncthreads();
    int b = threadIdx.x;
    hist_part[(size_t)blockIdx.x * 256 + b] = lh[b] + lh[256 + b] + lh[512 + b] + lh[768 + b];
}

__global__ __launch_bounds__(1024) void k_otsu(
        const unsigned* __restrict__ hist_part, int nparts,
        const float* __restrict__ minmax, float* __restrict__ thresh) {
    __shared__ unsigned csum[1024];
    __shared__ float counts[256], centers[256], tt[256];
    __shared__ float w1[256], s1[256], w2[256], s2[256], vv[256];
    int t = threadIdx.x;
    int b = t & 255, q = t >> 8;
    unsigned acc = 0;
    for (int k = q; k < nparts; k += 4)
        acc += hist_part[(size_t)k * 256 + b];
    csum[q * 256 + b] = acc;
    __syncthreads();
    if (t < 256) {
        unsigned c = csum[t] + csum[256 + t] + csum[512 + t] + csum[768 + t];
        float mn = minmax[0];
        float mx = minmax[1];
        float width = __fdiv_rn(__fsub_rn(mx, mn), 256.0f);
        counts[t] = (float)c;
        centers[t] = __fadd_rn(mn, __fmul_rn(width, __fadd_rn((float)t, 0.5f)));
        tt[t] = __fmul_rn(counts[t], centers[t]);
    }
    __syncthreads();
    if (t == 0) {
        float aw = 0.0f, as = 0.0f;
        for (int i = 0; i < 256; ++i) {
            aw = __fadd_rn(aw, counts[i]); w1[i] = aw;
            as = __fadd_rn(as, tt[i]);     s1[i] = as;
        }
        aw = 0.0f; as = 0.0f;
        for (int i = 255; i >= 0; --i) {
            aw = __fadd_rn(aw, counts[i]); w2[i] = aw;
            as = __fadd_rn(as, tt[i]);     s2[i] = as;
        }
    }
    __syncthreads();
    if (t < 255) {
        float m1 = __fdiv_rn(s1[t],     fmaxf(w1[t],     1.0f));
        float m2 = __fdiv_rn(s2[t + 1], fmaxf(w2[t + 1], 1.0f));
        float d  = __fsub_rn(m1, m2);
        vv[t] = __fmul_rn(__fmul_rn(w1[t], w2[t + 1]), __fmul_rn(d, d));
    }
    __syncthreads();
    if (t == 0) {
        float best = -1.0f; int bi = 0;
        for (int i = 0; i < 255; ++i) {
            float v = vv[i];
            if (v > best) { best = v; bi = i; }
        }
        *thresh = centers[bi];
    }
}

__global__ __launch_bounds__(256) void k_bin(
        float4* __restrict__ g4, const float* __restrict__ thresh, int npix4) {
    int i = blockIdx.x * blockDim.x + threadIdx.x;
    float th = *thresh;
    if (i < npix4) {
        float4 g = g4[i];
        float4 o;
        o.x = g.x > th ? 1.0f : 0.0f;
        o.y = g.y > th ? 1.0f : 0.0f;
        o.z = g.z > th ? 1.0f : 0.0f;
        o.w = g.w > th ? 1.0f : 0.0f;
        g4[i] = o;
    }
}

extern "C" void kernel_launch(void* const* d_in, const int* in_sizes, int n_in,
                              void* d_out, int out_size, void* d_ws, size_t ws_size,
                              hipStream_t stream) {
    const float4* in4 = (const float4*)d_in[0];
    float4* gray4 = (float4*)d_out;          // d_out doubles as the gray buffer

    int npix = in_sizes[0] / 3;              // 16*1024*1024
    int npix4 = npix / 4;
    int ntiles = npix / 1024;                // 16384

    const int NB = 1024;                     // 4 blocks/CU on 256 CUs, coop-safe
    // ws layout (all 4B-aligned)
    float* pmin = (float*)d_ws;                          // NB
    float* pmax = pmin + NB;                             // NB
    float* minmax = pmax + NB;                           // 2 (fallback only)
    float* thresh = minmax + 2;                          // 1
    unsigned* hist_part = (unsigned*)(thresh + 1);       // NB*256

    void* args[] = { (void*)&in4, (void*)&gray4, (void*)&pmin, (void*)&pmax,
                     (void*)&hist_part, (void*)&thresh, (void*)&ntiles, (void*)&npix4 };
    hipError_t err = hipLaunchCooperativeKernel((const void*)k_fused,
                                                dim3(NB), dim3(256), args, 0, stream);
    if (err != hipSuccess) {
        // deterministic fallback: same math, 5 launches
        (void)hipGetLastError();             // clear sticky error
        k_gray<<<2048, 256, 0, stream>>>(in4, gray4, pmin, pmax, ntiles);
        k_reduce<<<1, 256, 0, stream>>>(pmin, pmax, minmax, 2048);
        k_hist<<<NB, 256, 0, stream>>>((const float4*)d_out, minmax, hist_part, npix4);
        k_otsu<<<1, 1024, 0, stream>>>(hist_part, NB, minmax, thresh);
        k_bin<<<(npix4 + 255) / 256, 256, 0, stream>>>(gray4, thresh, npix4);
    }
}

// Round 6
// 371.875 us; speedup vs baseline: 1.9201x; 1.9201x over previous
//
#include <hip/hip_runtime.h>

// Otsu binarization: rgb(16,1024,1024,3) -> gray -> global otsu threshold -> {0,1}
//
// R2 lesson: same-cacheline global atomics serialize (~381us) -> none anywhere.
// R5 lesson: grid.sync() is ~100us each on MI355X (single-line cross-XCD atomic
//            spin) -> cooperative fusion abandoned. 3 plain launches instead:
//   K1 gray+minmax partials -> K2 hist (inline minmax reduce) -> K3 bin
//   (inline minmax reduce + hist-partial sum + bit-exact Otsu per block).
// Redundant per-block scalar work is identical FP ops everywhere -> deterministic.
//
// FP discipline (absmax=0 verified R3): __f*_rn everywhere, einsum L-to-R
// order, true division for bin index, sequential cumsums on one thread.
// One flipped pixel fails absmax, so no FMA/rcp tricks.

static constexpr float W0 = 0.2989f;
static constexpr float W1 = 0.5870f;
static constexpr float W2 = 0.1140f;

static constexpr int GRAY_BLOCKS = 4096;   // 8 blocks/CU worth of barrier overlap
static constexpr int HIST_BLOCKS = 512;    // hist partials: 512*256*4B = 512 KB
static constexpr int BIN_BLOCKS  = 1024;   // 4/CU saturates the 134 MB stream

__device__ __forceinline__ float gray_of(float r, float g, float b) {
    // einsum 'bhwc,c->bhw': ((r*w0) + (g*w1)) + (b*w2), rn each step, no fma
    return __fadd_rn(__fadd_rn(__fmul_rn(r, W0), __fmul_rn(g, W1)), __fmul_rn(b, W2));
}

__device__ __forceinline__ void wave_minmax(float& lmin, float& lmax) {
    #pragma unroll
    for (int off = 32; off > 0; off >>= 1) {
        lmin = fminf(lmin, __shfl_down(lmin, off));
        lmax = fmaxf(lmax, __shfl_down(lmax, off));
    }
}

// Block-wide reduce of the K1 min/max partial arrays (L2-resident, 16 KB).
// Every calling block gets the same bit pattern.
__device__ __forceinline__ void reduce_partials(
        const float* __restrict__ pmin, const float* __restrict__ pmax,
        int n, float& out_mn, float& out_mx) {
    __shared__ float smin[4], smax[4];
    int t = threadIdx.x;
    float lmin = __uint_as_float(0x7f800000u);   // +inf
    float lmax = -lmin;
    for (int i = t; i < n; i += 256) {
        lmin = fminf(lmin, pmin[i]);
        lmax = fmaxf(lmax, pmax[i]);
    }
    wave_minmax(lmin, lmax);
    if ((t & 63) == 0) { smin[t >> 6] = lmin; smax[t >> 6] = lmax; }
    __syncthreads();
    out_mn = fminf(fminf(smin[0], smin[1]), fminf(smin[2], smin[3]));
    out_mx = fmaxf(fmaxf(smax[0], smax[1]), fmaxf(smax[2], smax[3]));
    __syncthreads();   // smin/smax free for reuse by caller
}

// ---- K1: gray + per-block min/max partials (LDS-staged coalesced loads) ----
__global__ __launch_bounds__(256) void k_gray(
        const float4* __restrict__ in4, float4* __restrict__ gray4,
        float* __restrict__ pmin, float* __restrict__ pmax, int ntiles) {
    __shared__ float4 sv[768];
    int t = threadIdx.x;
    float lmin = __uint_as_float(0x7f800000u);
    float lmax = -lmin;
    for (int tile = blockIdx.x; tile < ntiles; tile += gridDim.x) {
        const float4* src = in4 + (size_t)tile * 768;
        float4 v0 = src[t];            // issue before barrier: latency overlaps
        float4 v1 = src[t + 256];
        float4 v2 = src[t + 512];
        __syncthreads();               // prior iteration's LDS reads done
        sv[t] = v0; sv[t + 256] = v1; sv[t + 512] = v2;
        __syncthreads();
        float4 a = sv[3 * t + 0];
        float4 b = sv[3 * t + 1];
        float4 c = sv[3 * t + 2];
        float g0 = gray_of(a.x, a.y, a.z);
        float g1 = gray_of(a.w, b.x, b.y);
        float g2 = gray_of(b.z, b.w, c.x);
        float g3 = gray_of(c.y, c.z, c.w);
        float4 o; o.x = g0; o.y = g1; o.z = g2; o.w = g3;
        gray4[(size_t)tile * 256 + t] = o;
        lmin = fminf(lmin, fminf(fminf(g0, g1), fminf(g2, g3)));
        lmax = fmaxf(lmax, fmaxf(fmaxf(g0, g1), fmaxf(g2, g3)));
    }
    wave_minmax(lmin, lmax);
    __shared__ float smin[4], smax[4];
    if ((t & 63) == 0) { smin[t >> 6] = lmin; smax[t >> 6] = lmax; }
    __syncthreads();
    if (t == 0) {
        pmin[blockIdx.x] = fminf(fminf(smin[0], smin[1]), fminf(smin[2], smin[3]));
        pmax[blockIdx.x] = fmaxf(fmaxf(smax[0], smax[1]), fmaxf(smax[2], smax[3]));
    }
}

// ---- K2: inline minmax reduce + per-wave LDS hists -> per-block partial ----
__global__ __launch_bounds__(256) void k_hist(
        const float4* __restrict__ gray4,
        const float* __restrict__ pmin, const float* __restrict__ pmax,
        unsigned* __restrict__ hist_part, int npix4) {
    float mn, mx;
    reduce_partials(pmin, pmax, GRAY_BLOCKS, mn, mx);
    float width = __fdiv_rn(__fsub_rn(mx, mn), 256.0f);

    __shared__ unsigned lh[1024];      // one 256-bin hist per wave
    for (int j = threadIdx.x; j < 1024; j += 256) lh[j] = 0u;
    __syncthreads();
    unsigned* myh = &lh[(threadIdx.x >> 6) << 8];
    int stride = gridDim.x * 256;
    for (int i = blockIdx.x * 256 + threadIdx.x; i < npix4; i += stride) {
        float4 g = gray4[i];
        // reference: int32((x - mn) / width) clipped to [0,255] — true division
        int i0 = (int)__fdiv_rn(__fsub_rn(g.x, mn), width);
        int i1 = (int)__fdiv_rn(__fsub_rn(g.y, mn), width);
        int i2 = (int)__fdiv_rn(__fsub_rn(g.z, mn), width);
        int i3 = (int)__fdiv_rn(__fsub_rn(g.w, mn), width);
        i0 = min(max(i0, 0), 255);
        i1 = min(max(i1, 0), 255);
        i2 = min(max(i2, 0), 255);
        i3 = min(max(i3, 0), 255);
        atomicAdd(&myh[i0], 1u);       // LDS atomics only
        atomicAdd(&myh[i1], 1u);
        atomicAdd(&myh[i2], 1u);
        atomicAdd(&myh[i3], 1u);
    }
    __syncthreads();
    int b = threadIdx.x;               // one bin per thread, coalesced store
    hist_part[(size_t)blockIdx.x * 256 + b] =
        lh[b] + lh[256 + b] + lh[512 + b] + lh[768 + b];
}

// ---- K3: per-block redundant Otsu (bit-exact) + binarize ----
__global__ __launch_bounds__(256) void k_bin(
        float4* __restrict__ g4,
        const float* __restrict__ pmin, const float* __restrict__ pmax,
        const unsigned* __restrict__ hist_part, int npix4) {
    float mn, mx;
    reduce_partials(pmin, pmax, GRAY_BLOCKS, mn, mx);
    float width = __fdiv_rn(__fsub_rn(mx, mn), 256.0f);

    __shared__ float counts[256], centers[256], tt[256];
    __shared__ float w1[256], s1[256], w2[256], s2[256], vv[256];
    __shared__ float s_th;
    int t = threadIdx.x;

    // sum the 512 hist partials: thread t owns bin t; loads coalesced per k
    unsigned c = 0;
    #pragma unroll 8
    for (int k = 0; k < HIST_BLOCKS; ++k)
        c += hist_part[(size_t)k * 256 + t];
    counts[t] = (float)c;              // exact: counts <= 2^24
    centers[t] = __fadd_rn(mn, __fmul_rn(width, __fadd_rn((float)t, 0.5f)));
    tt[t] = __fmul_rn(counts[t], centers[t]);
    __syncthreads();
    if (t == 0) {
        float aw = 0.0f, as = 0.0f;
        #pragma unroll 16
        for (int i = 0; i < 256; ++i) {        // forward cumsum (np order)
            aw = __fadd_rn(aw, counts[i]); w1[i] = aw;
            as = __fadd_rn(as, tt[i]);     s1[i] = as;
        }
        aw = 0.0f; as = 0.0f;
        #pragma unroll 16
        for (int i = 255; i >= 0; --i) {       // reversed cumsum
            aw = __fadd_rn(aw, counts[i]); w2[i] = aw;
            as = __fadd_rn(as, tt[i]);     s2[i] = as;
        }
    }
    __syncthreads();
    if (t < 255) {
        float m1 = __fdiv_rn(s1[t],     fmaxf(w1[t],     1.0f));
        float m2 = __fdiv_rn(s2[t + 1], fmaxf(w2[t + 1], 1.0f));
        float d  = __fsub_rn(m1, m2);
        // python eval order: (w1*w2) * (d**2)
        vv[t] = __fmul_rn(__fmul_rn(w1[t], w2[t + 1]), __fmul_rn(d, d));
    }
    __syncthreads();
    if (t == 0) {
        float best = -1.0f; int bi = 0;
        #pragma unroll 16
        for (int i = 0; i < 255; ++i) {        // strict > == first argmax
            float v = vv[i];
            if (v > best) { best = v; bi = i; }
        }
        s_th = centers[bi];
    }
    __syncthreads();
    const float th = s_th;

    int stride = gridDim.x * 256;
    for (int i = blockIdx.x * 256 + t; i < npix4; i += stride) {
        float4 g = g4[i];
        float4 o;
        o.x = g.x > th ? 1.0f : 0.0f;
        o.y = g.y > th ? 1.0f : 0.0f;
        o.z = g.z > th ? 1.0f : 0.0f;
        o.w = g.w > th ? 1.0f : 0.0f;
        g4[i] = o;
    }
}

extern "C" void kernel_launch(void* const* d_in, const int* in_sizes, int n_in,
                              void* d_out, int out_size, void* d_ws, size_t ws_size,
                              hipStream_t stream) {
    const float4* in4 = (const float4*)d_in[0];
    float4* gray4 = (float4*)d_out;          // d_out doubles as the gray buffer

    int npix = in_sizes[0] / 3;              // 16*1024*1024
    int npix4 = npix / 4;                    // 4M float4s
    int ntiles = npix / 1024;                // 16384 tiles of 1024 pixels

    // ws layout (all 4B-aligned):
    float* pmin = (float*)d_ws;                          // GRAY_BLOCKS
    float* pmax = pmin + GRAY_BLOCKS;                    // GRAY_BLOCKS
    unsigned* hist_part = (unsigned*)(pmax + GRAY_BLOCKS); // HIST_BLOCKS*256

    k_gray<<<GRAY_BLOCKS, 256, 0, stream>>>(in4, gray4, pmin, pmax, ntiles);
    k_hist<<<HIST_BLOCKS, 256, 0, stream>>>((const float4*)d_out, pmin, pmax,
                                            hist_part, npix4);
    k_bin<<<BIN_BLOCKS, 256, 0, stream>>>(gray4, pmin, pmax, hist_part, npix4);
}

// Round 7
// 357.757 us; speedup vs baseline: 1.9958x; 1.0395x over previous
//
#include <hip/hip_runtime.h>

// Otsu binarization: rgb(16,1024,1024,3) -> gray -> global otsu threshold -> {0,1}
//
// R2 lesson: same-cacheline global atomics serialize (~381us) -> none anywhere.
// R5 lesson: grid.sync() ~100us each on MI355X (cross-XCD atomic spin) -> no
//            cooperative fusion. Plain launches cost only ~8us each (R3 vs R6).
// R6 lesson: fills (~130us) are fixed harness overhead; kernels+gaps ~240us vs
//            ~75us traffic ideal -> cut k_gray's per-4-pixel double barrier
//            (direct strided loads; R1/R2 never actually measured that pattern
//            un-atomic-bound) and k_bin's redundant 512MB L2 prelude (k_otsu).
//
// FP discipline (absmax=0 verified R3/R6): __f*_rn everywhere, einsum L-to-R
// order, true division for bin index, sequential cumsums on one thread.
// One flipped pixel fails absmax, so no FMA/rcp tricks.

static constexpr float W0 = 0.2989f;
static constexpr float W1 = 0.5870f;
static constexpr float W2 = 0.1140f;

static constexpr int GRAY_BLOCKS = 4096;   // 1024 pixel-groups (4096 px) each
static constexpr int HIST_BLOCKS = 512;    // partials: 512*256*4B = 512 KB (L2)
static constexpr int BIN_BLOCKS  = 4096;   // flat, 4 float4 per thread

__device__ __forceinline__ float gray_of(float r, float g, float b) {
    // einsum 'bhwc,c->bhw': ((r*w0) + (g*w1)) + (b*w2), rn each step, no fma
    return __fadd_rn(__fadd_rn(__fmul_rn(r, W0), __fmul_rn(g, W1)), __fmul_rn(b, W2));
}

__device__ __forceinline__ void wave_minmax(float& lmin, float& lmax) {
    #pragma unroll
    for (int off = 32; off > 0; off >>= 1) {
        lmin = fminf(lmin, __shfl_down(lmin, off));
        lmax = fmaxf(lmax, __shfl_down(lmax, off));
    }
}

// Block-wide reduce of the k_gray min/max partials (L2-resident, 32 KB).
// Deterministic: every calling block computes the same bit pattern.
__device__ __forceinline__ void reduce_partials(
        const float* __restrict__ pmin, const float* __restrict__ pmax,
        int n, int nthreads, float& out_mn, float& out_mx) {
    __shared__ float smin[16], smax[16];
    int t = threadIdx.x;
    float lmin = __uint_as_float(0x7f800000u);   // +inf
    float lmax = -lmin;
    for (int i = t; i < n; i += nthreads) {
        lmin = fminf(lmin, pmin[i]);
        lmax = fmaxf(lmax, pmax[i]);
    }
    wave_minmax(lmin, lmax);
    int nw = nthreads >> 6;
    if ((t & 63) == 0) { smin[t >> 6] = lmin; smax[t >> 6] = lmax; }
    __syncthreads();
    float m = smin[0], M = smax[0];
    for (int w = 1; w < nw; ++w) { m = fminf(m, smin[w]); M = fmaxf(M, smax[w]); }
    out_mn = m; out_mx = M;
    __syncthreads();   // smin/smax reusable by caller
}

// ---- K1: gray + per-block min/max partials. Direct loads, no LDS/barriers.
// Thread handles 4 pixel-groups (16 px, 12 float4 loads in flight). Within a
// wave the 3 stride-48B loads of a group cover a contiguous 3KB span -> L1
// line reuse, no HBM over-fetch.
__global__ __launch_bounds__(256) void k_gray(
        const float4* __restrict__ in4, float4* __restrict__ gray4,
        float* __restrict__ pmin, float* __restrict__ pmax) {
    int t = threadIdx.x;
    int base = blockIdx.x * 1024;              // 1024 groups per block
    float lmin = __uint_as_float(0x7f800000u);
    float lmax = -lmin;
    #pragma unroll
    for (int j = 0; j < 4; ++j) {
        int g = base + j * 256 + t;
        const float4* src = in4 + 3 * (size_t)g;
        float4 a = src[0];
        float4 b = src[1];
        float4 c = src[2];
        float g0 = gray_of(a.x, a.y, a.z);
        float g1 = gray_of(a.w, b.x, b.y);
        float g2 = gray_of(b.z, b.w, c.x);
        float g3 = gray_of(c.y, c.z, c.w);
        float4 o; o.x = g0; o.y = g1; o.z = g2; o.w = g3;
        gray4[g] = o;
        lmin = fminf(lmin, fminf(fminf(g0, g1), fminf(g2, g3)));
        lmax = fmaxf(lmax, fmaxf(fmaxf(g0, g1), fmaxf(g2, g3)));
    }
    wave_minmax(lmin, lmax);
    __shared__ float smin[4], smax[4];
    if ((t & 63) == 0) { smin[t >> 6] = lmin; smax[t >> 6] = lmax; }
    __syncthreads();
    if (t == 0) {
        pmin[blockIdx.x] = fminf(fminf(smin[0], smin[1]), fminf(smin[2], smin[3]));
        pmax[blockIdx.x] = fmaxf(fmaxf(smax[0], smax[1]), fmaxf(smax[2], smax[3]));
    }
}

// ---- K2: inline minmax reduce + per-wave LDS hists -> per-block partial ----
__global__ __launch_bounds__(256) void k_hist(
        const float4* __restrict__ gray4,
        const float* __restrict__ pmin, const float* __restrict__ pmax,
        unsigned* __restrict__ hist_part, int npix4) {
    float mn, mx;
    reduce_partials(pmin, pmax, GRAY_BLOCKS, 256, mn, mx);
    float width = __fdiv_rn(__fsub_rn(mx, mn), 256.0f);

    __shared__ unsigned lh[1024];      // one 256-bin hist per wave
    for (int j = threadIdx.x; j < 1024; j += 256) lh[j] = 0u;
    __syncthreads();
    unsigned* myh = &lh[(threadIdx.x >> 6) << 8];
    int stride = gridDim.x * 256;
    for (int i = blockIdx.x * 256 + threadIdx.x; i < npix4; i += stride) {
        float4 g = gray4[i];
        // reference: int32((x - mn) / width) clipped to [0,255] — true division
        int i0 = (int)__fdiv_rn(__fsub_rn(g.x, mn), width);
        int i1 = (int)__fdiv_rn(__fsub_rn(g.y, mn), width);
        int i2 = (int)__fdiv_rn(__fsub_rn(g.z, mn), width);
        int i3 = (int)__fdiv_rn(__fsub_rn(g.w, mn), width);
        i0 = min(max(i0, 0), 255);
        i1 = min(max(i1, 0), 255);
        i2 = min(max(i2, 0), 255);
        i3 = min(max(i3, 0), 255);
        atomicAdd(&myh[i0], 1u);       // LDS atomics only
        atomicAdd(&myh[i1], 1u);
        atomicAdd(&myh[i2], 1u);
        atomicAdd(&myh[i3], 1u);
    }
    __syncthreads();
    int b = threadIdx.x;               // one bin per thread, coalesced store
    hist_part[(size_t)blockIdx.x * 256 + b] =
        lh[b] + lh[256 + b] + lh[512 + b] + lh[768 + b];
}

// ---- K3: single block -> final histogram + bit-exact sequential Otsu ----
__global__ __launch_bounds__(1024) void k_otsu(
        const unsigned* __restrict__ hist_part,
        const float* __restrict__ pmin, const float* __restrict__ pmax,
        float* __restrict__ thresh) {
    float mn, mx;
    reduce_partials(pmin, pmax, GRAY_BLOCKS, 1024, mn, mx);
    float width = __fdiv_rn(__fsub_rn(mx, mn), 256.0f);

    __shared__ unsigned csum[1024];
    __shared__ float counts[256], centers[256], tt[256];
    __shared__ float w1[256], s1[256], w2[256], s2[256], vv[256];
    int t = threadIdx.x;
    int b = t & 255, q = t >> 8;
    unsigned acc = 0;
    #pragma unroll 8
    for (int k = q; k < HIST_BLOCKS; k += 4)   // coalesced: thread b -> k*256+b
        acc += hist_part[(size_t)k * 256 + b];
    csum[q * 256 + b] = acc;
    __syncthreads();
    if (t < 256) {
        unsigned c = csum[t] + csum[256 + t] + csum[512 + t] + csum[768 + t];
        counts[t] = (float)c;                  // exact: counts <= 2^24
        centers[t] = __fadd_rn(mn, __fmul_rn(width, __fadd_rn((float)t, 0.5f)));
        tt[t] = __fmul_rn(counts[t], centers[t]);
    }
    __syncthreads();
    if (t == 0) {
        float aw = 0.0f, as = 0.0f;
        #pragma unroll 16
        for (int i = 0; i < 256; ++i) {        // forward cumsum (np order)
            aw = __fadd_rn(aw, counts[i]); w1[i] = aw;
            as = __fadd_rn(as, tt[i]);     s1[i] = as;
        }
        aw = 0.0f; as = 0.0f;
        #pragma unroll 16
        for (int i = 255; i >= 0; --i) {       // reversed cumsum
            aw = __fadd_rn(aw, counts[i]); w2[i] = aw;
            as = __fadd_rn(as, tt[i]);     s2[i] = as;
        }
    }
    __syncthreads();
    if (t < 255) {
        float m1 = __fdiv_rn(s1[t],     fmaxf(w1[t],     1.0f));
        float m2 = __fdiv_rn(s2[t + 1], fmaxf(w2[t + 1], 1.0f));
        float d  = __fsub_rn(m1, m2);
        // python eval order: (w1*w2) * (d**2)
        vv[t] = __fmul_rn(__fmul_rn(w1[t], w2[t + 1]), __fmul_rn(d, d));
    }
    __syncthreads();
    if (t == 0) {
        float best = -1.0f; int bi = 0;
        #pragma unroll 16
        for (int i = 0; i < 255; ++i) {        // strict > == first argmax
            float v = vv[i];
            if (v > best) { best = v; bi = i; }
        }
        *thresh = centers[bi];
    }
}

// ---- K4: pure stream binarize, threshold via 1-float broadcast load ----
__global__ __launch_bounds__(256) void k_bin(
        float4* __restrict__ g4, const float* __restrict__ thresh) {
    const float th = thresh[0];
    int t = threadIdx.x;
    int base = blockIdx.x * 1024;
    #pragma unroll
    for (int j = 0; j < 4; ++j) {
        int i = base + j * 256 + t;
        float4 g = g4[i];
        float4 o;
        o.x = g.x > th ? 1.0f : 0.0f;
        o.y = g.y > th ? 1.0f : 0.0f;
        o.z = g.z > th ? 1.0f : 0.0f;
        o.w = g.w > th ? 1.0f : 0.0f;
        g4[i] = o;
    }
}

extern "C" void kernel_launch(void* const* d_in, const int* in_sizes, int n_in,
                              void* d_out, int out_size, void* d_ws, size_t ws_size,
                              hipStream_t stream) {
    const float4* in4 = (const float4*)d_in[0];
    float4* gray4 = (float4*)d_out;          // d_out doubles as the gray buffer

    int npix = in_sizes[0] / 3;              // 16*1024*1024
    int npix4 = npix / 4;                    // 4,194,304 float4 groups

    // ws layout (all 4B-aligned):
    float* pmin = (float*)d_ws;                             // GRAY_BLOCKS
    float* pmax = pmin + GRAY_BLOCKS;                       // GRAY_BLOCKS
    float* thresh = pmax + GRAY_BLOCKS;                     // 1
    unsigned* hist_part = (unsigned*)(thresh + 1);          // HIST_BLOCKS*256

    k_gray<<<GRAY_BLOCKS, 256, 0, stream>>>(in4, gray4, pmin, pmax);
    k_hist<<<HIST_BLOCKS, 256, 0, stream>>>((const float4*)d_out, pmin, pmax,
                                            hist_part, npix4);
    k_otsu<<<1, 1024, 0, stream>>>(hist_part, pmin, pmax, thresh);
    k_bin<<<BIN_BLOCKS, 256, 0, stream>>>(gray4, thresh);
}